// Round 13
// baseline (78.412 us; speedup 1.0000x reference)
//
#include <hip/hip_runtime.h>
#include <math.h>

#define MARGIN 0.3f

typedef short bf16x8 __attribute__((ext_vector_type(8)));
typedef float f32x16 __attribute__((ext_vector_type(16)));
typedef unsigned int u32;
typedef const __attribute__((address_space(1))) u32* gp_t;
typedef __attribute__((address_space(3))) u32* lp_t;

__device__ __forceinline__ unsigned short f2bf_rne(float x) {
    unsigned b = __float_as_uint(x);
    unsigned r = b + 0x7FFFu + ((b >> 16) & 1u);
    return (unsigned short)(r >> 16);
}
// family table {0,1,2,1,3,3} packed 2 bits/entry
__device__ __forceinline__ int fam_of(int lbl) { return (0xF64 >> (2 * lbl)) & 3; }

// ---------------- K1: deterministic counting sort by family (+ counter init) ----------------
__global__ __launch_bounds__(1024) void sort_kernel(const int* __restrict__ labels,
                                                    int* __restrict__ posOf,
                                                    unsigned char* __restrict__ famSorted,
                                                    int* __restrict__ famLoHi,
                                                    unsigned* __restrict__ counters, int B) {
    const int t = threadIdx.x;
    const int lane = t & 63, w = t >> 6;
    if (t < 2) counters[t] = 0;   // re-armed every call (deterministic replays)
    int lc[4] = {0, 0, 0, 0};
    int lf[8], lr[8];
#pragma unroll
    for (int j = 0; j < 8; j++) {
        int f = fam_of(labels[t * 8 + j]);
        lf[j] = f; lr[j] = lc[f]++;
    }
    int inc[4];
#pragma unroll
    for (int f = 0; f < 4; f++) {
        int v = lc[f];
#pragma unroll
        for (int o = 1; o < 64; o <<= 1) {
            int u = __shfl_up(v, o, 64);
            if (lane >= o) v += u;
        }
        inc[f] = v;
    }
    __shared__ int waveTot[16][4], waveBase[16][4], famBase[4], famTotS[4];
    if (lane == 63)
#pragma unroll
        for (int f = 0; f < 4; f++) waveTot[w][f] = inc[f];
    __syncthreads();
    if (t < 64) {
        int f = t >> 4, ww = t & 15;
        int v = waveTot[ww][f];
#pragma unroll
        for (int o = 1; o < 16; o <<= 1) {
            int u = __shfl_up(v, o, 64);
            if ((t & 15) >= o) v += u;
        }
        waveBase[ww][f] = v - waveTot[ww][f];
        if (ww == 15) famTotS[f] = v;
    }
    __syncthreads();
    if (t == 0) {
        int b = 0;
#pragma unroll
        for (int f = 0; f < 4; f++) {
            famBase[f] = b; famLoHi[f] = b; b += famTotS[f]; famLoHi[4 + f] = b;
        }
    }
    __syncthreads();
    int base[4];
#pragma unroll
    for (int f = 0; f < 4; f++) base[f] = famBase[f] + waveBase[w][f] + (inc[f] - lc[f]);
#pragma unroll
    for (int j = 0; j < 8; j++) {
        int pos = base[lf[j]] + lr[j];
        posOf[t * 8 + j] = pos;
        famSorted[pos] = (unsigned char)lf[j];
    }
}

// ---------------- K2: normalize + bf16 round + 32-entity frag pack ----------------
// Strip = 32 sorted rows, 2048 bf16 (4KB):
//   idx = strip*2048 + kw*512 + half*256 + (pos&31)*8 + e
// where k = kw*16 + half*8 + e. Fragment read (32x32x16): lane l takes 16B at
// strip*2048 + kw*512 + l*8 -> entity l&31, k-half l>>5. A and B share the map,
// so k-permutation errors cancel; entity map matches C/D col=lane&31.
__global__ __launch_bounds__(256) void normpack_kernel(const float* __restrict__ emb,
                                                       const int* __restrict__ posOf,
                                                       short* __restrict__ pack, int B) {
    const int lane = threadIdx.x & 63;
    const int wid  = threadIdx.x >> 6;
    const int row  = blockIdx.x * 4 + wid;
    float x = emb[(size_t)row * 64 + lane];
    float ss = x * x;
#pragma unroll
    for (int o = 32; o > 0; o >>= 1) ss += __shfl_xor(ss, o, 64);
    float n = fmaxf(sqrtf(ss), 1e-12f);
    unsigned short h = f2bf_rne(x / n);
    int pos = posOf[row];
    size_t idx = (size_t)(pos >> 5) * 2048 + (size_t)(lane >> 4) * 512 +
                 (size_t)((lane >> 3) & 1) * 256 + (size_t)(pos & 31) * 8 + (lane & 7);
    pack[idx] = (short)h;
}

// ---------------- K3: 32x32 MFMA GEMM + lane-local min/max + fused tail ----------------
// Grid 512 blocks (16 row-blocks x 32 col-chunks) = 2 blocks/CU. Block: 512 rows
// x 256 cols; wave = 128 rows (4 strips of 32). B chunk (32KB) staged once.
// Swapped operands: D[j][i], i=lane&31 row, 16 j's in regs -> min/max lane-local.
// Tail: last 32 arriving blocks barrier-spin then do rowloss + finalize.
__global__ __launch_bounds__(256, 2) void gemm_tail_kernel(
    const short* __restrict__ pack,
    const unsigned char* __restrict__ famSorted, const int* __restrict__ famLoHi,
    float* __restrict__ pMin, float* __restrict__ pMax,
    unsigned* __restrict__ counters, float* __restrict__ partial,
    float* __restrict__ out, int B) {
    __shared__ short ldsB[16384];   // 32 KB
    const int t    = threadIdx.x;
    const int lane = t & 63;
    const int wid  = t >> 6;
    const int half = lane >> 5;
    const int il   = lane & 31;
    const int rowBlock = blockIdx.x & 15;
    const int colBlock = blockIdx.x >> 4;
    const int rowBase  = rowBlock * 512 + wid * 128;
    const int aStrip0  = rowBase >> 5;
    const int jChunk0  = colBlock * 256;
    const int jStrip0  = jChunk0 >> 5;

    // A (row) fragments: 4 strips x 4 kw = 64 VGPRs, resident all sweep.
    bf16x8 aH[4][4];
#pragma unroll
    for (int s = 0; s < 4; s++) {
        const short* pA = pack + (size_t)(aStrip0 + s) * 2048;
#pragma unroll
        for (int kw = 0; kw < 4; kw++)
            aH[s][kw] = *(const bf16x8*)(pA + kw * 512 + lane * 8);
    }
    // Stage B chunk: 32 KB linear; each wave 8 x 1KB global_load_lds.
    {
        const char* src = (const char*)(pack + (size_t)jStrip0 * 2048);
#pragma unroll
        for (int i = 0; i < 8; i++) {
            int off = wid * 8192 + i * 1024;
            __builtin_amdgcn_global_load_lds((gp_t)(src + off + lane * 16),
                                             (lp_t)((char*)ldsB + off), 16, 0, 0);
        }
    }
    // Per-strip (32 sorted rows) family classification.
    int sLo[4], sHi[4], sUni[4];
#pragma unroll
    for (int s = 0; s < 4; s++) {
        int f0  = famSorted[rowBase + s * 32];
        int f31 = famSorted[rowBase + s * 32 + 31];
        sUni[s] = __builtin_amdgcn_readfirstlane((f0 == f31) ? 1 : 0);
        sLo[s]  = __builtin_amdgcn_readfirstlane(famLoHi[f0]);
        sHi[s]  = __builtin_amdgcn_readfirstlane(famLoHi[4 + f0]);
    }
    const f32x16 zq = {0.f};
    float mn[4] = {1e30f, 1e30f, 1e30f, 1e30f};
    float mx[4] = {-1e30f, -1e30f, -1e30f, -1e30f};

    __syncthreads();   // staging complete (vmcnt drained before barrier)

#pragma unroll
    for (int pr = 0; pr < 4; pr++) {   // pairs of 32-col tiles (64 cols)
        const int j0 = jChunk0 + pr * 64;
        const short* pB0 = ldsB + pr * 4096;
        const short* pB1 = pB0 + 2048;
        bf16x8 bA[4], bB[4];
#pragma unroll
        for (int kw = 0; kw < 4; kw++) {
            bA[kw] = *(const bf16x8*)(pB0 + kw * 512 + lane * 8);
            bB[kw] = *(const bf16x8*)(pB1 + kw * 512 + lane * 8);
        }
#pragma unroll
        for (int s = 0; s < 4; s++) {
            f32x16 accA = __builtin_amdgcn_mfma_f32_32x32x16_bf16(bA[0], aH[s][0], zq, 0, 0, 0);
            f32x16 accB = __builtin_amdgcn_mfma_f32_32x32x16_bf16(bB[0], aH[s][0], zq, 0, 0, 0);
            accA = __builtin_amdgcn_mfma_f32_32x32x16_bf16(bA[1], aH[s][1], accA, 0, 0, 0);
            accB = __builtin_amdgcn_mfma_f32_32x32x16_bf16(bB[1], aH[s][1], accB, 0, 0, 0);
            accA = __builtin_amdgcn_mfma_f32_32x32x16_bf16(bA[2], aH[s][2], accA, 0, 0, 0);
            accB = __builtin_amdgcn_mfma_f32_32x32x16_bf16(bB[2], aH[s][2], accB, 0, 0, 0);
            accA = __builtin_amdgcn_mfma_f32_32x32x16_bf16(bA[3], aH[s][3], accA, 0, 0, 0);
            accB = __builtin_amdgcn_mfma_f32_32x32x16_bf16(bB[3], aH[s][3], accB, 0, 0, 0);

            if (sUni[s] && j0 >= sLo[s] && j0 + 64 <= sHi[s]) {
                // both tiles fully same-family (diag dot~1 never the min) -> v_min3
#pragma unroll
                for (int r = 0; r < 16; r++)
                    mn[s] = fminf(fminf(mn[s], accA[r]), accB[r]);
            } else if (sUni[s] && (j0 >= sHi[s] || j0 + 64 <= sLo[s])) {
#pragma unroll
                for (int r = 0; r < 16; r++)
                    mx[s] = fmaxf(fmaxf(mx[s], accA[r]), accB[r]);
            } else {
                // boundary pair: per-element family compare
                int fi = famSorted[rowBase + s * 32 + il];
                u32 wA[4], wB[4];
#pragma unroll
                for (int q = 0; q < 4; q++) {
                    wA[q] = *(const u32*)(famSorted + j0 + q * 8 + 4 * half);
                    wB[q] = *(const u32*)(famSorted + j0 + 32 + q * 8 + 4 * half);
                }
#pragma unroll
                for (int r = 0; r < 16; r++) {
                    // j = (r&3) + 8*(r>>2) + 4*half  (HW C/D row map, m74/m101)
                    int fjA = (int)((wA[r >> 2] >> ((r & 3) * 8)) & 255u);
                    int fjB = (int)((wB[r >> 2] >> ((r & 3) * 8)) & 255u);
                    bool sameA = (fjA == fi), sameB = (fjB == fi);
                    mn[s] = fminf(mn[s], sameA ? accA[r] : 1e30f);
                    mx[s] = fmaxf(mx[s], sameA ? -1e30f : accA[r]);
                    mn[s] = fminf(mn[s], sameB ? accB[r] : 1e30f);
                    mx[s] = fmaxf(mx[s], sameB ? -1e30f : accB[r]);
                }
            }
        }
    }

    // Combine the two lane-halves (rows i = lane&31): 1 shfl round, then store.
#pragma unroll
    for (int s = 0; s < 4; s++) {
        float mnv = fminf(mn[s], __shfl_xor(mn[s], 32, 64));
        float mxv = fmaxf(mx[s], __shfl_xor(mx[s], 32, 64));
        if (half == 0) {
            int row = rowBase + s * 32 + il;   // sorted-row index, 32-wide coalesced
            pMin[(size_t)colBlock * B + row] = mnv;
            pMax[(size_t)colBlock * B + row] = mxv;
        }
    }

    // ---- fused tail: last 32 arriving blocks do rowloss + finalize ----
    __threadfence();
    __shared__ unsigned sDone;
    if (t == 0) sDone = atomicAdd(&counters[0], 1u);
    __syncthreads();
    unsigned done = sDone;
    if (done >= 480u) {
        if (t == 0) { while (atomicAdd(&counters[0], 0u) < 512u) {} }
        __syncthreads();
        __threadfence();
        int slice = (int)done - 480;      // 0..31, each exactly once
        int row = slice * 256 + t;
        float rmn = 1e30f, rmx = -1e30f;
#pragma unroll 8
        for (int cn = 0; cn < 32; cn++) {
            rmn = fminf(rmn, pMin[(size_t)cn * B + row]);
            rmx = fmaxf(rmx, pMax[(size_t)cn * B + row]);
        }
        float sum = 0.f, cnt = 0.f;
        if (rmn < 1e29f && rmx > -1e29f) {   // has same && has diff
            sum = fmaxf(rmx - rmn + MARGIN, 0.f);   // relu(d_pos - d_neg + margin)
            cnt = 1.f;
        }
#pragma unroll
        for (int o = 32; o > 0; o >>= 1) {
            sum += __shfl_xor(sum, o, 64);
            cnt += __shfl_xor(cnt, o, 64);
        }
        __shared__ float sS[4], sC[4];
        if (lane == 0) { sS[wid] = sum; sC[wid] = cnt; }
        __syncthreads();
        if (t == 0) {
            partial[slice]      = sS[0] + sS[1] + sS[2] + sS[3];
            partial[64 + slice] = sC[0] + sC[1] + sC[2] + sC[3];
            __threadfence();
            unsigned d2 = atomicAdd(&counters[1], 1u);
            if (d2 == 31u) {
                __threadfence();
                float S = 0.f, C = 0.f;
                for (int i = 0; i < 32; i++) { S += partial[i]; C += partial[64 + i]; }
                out[0] = S / fmaxf(C, 1.f);
            }
        }
    }
}

extern "C" void kernel_launch(void* const* d_in, const int* in_sizes, int n_in,
                              void* d_out, int out_size, void* d_ws, size_t ws_size,
                              hipStream_t stream) {
    const float* emb    = (const float*)d_in[0];
    const int*   labels = (const int*)d_in[1];
    const int B = in_sizes[1];   // 8192, D == 64

    char* base = (char*)d_ws;
    size_t off = 0;
    auto alloc = [&](size_t bytes) -> char* {
        char* p = base + off;
        off = (off + bytes + 255) & ~(size_t)255;
        return p;
    };
    int*           posOf     = (int*)alloc((size_t)B * 4);
    unsigned char* famSorted = (unsigned char*)alloc((size_t)B);
    int*           famLoHi   = (int*)alloc(64);
    unsigned*      counters  = (unsigned*)alloc(64);
    short*         pack      = (short*)alloc((size_t)B * 64 * 2);  // hi-only, 1MB
    float*         pMin      = (float*)alloc((size_t)32 * B * 4);
    float*         pMax      = (float*)alloc((size_t)32 * B * 4);
    float*         partial   = (float*)alloc(128 * 4);

    sort_kernel<<<1, 1024, 0, stream>>>(labels, posOf, famSorted, famLoHi, counters, B);
    normpack_kernel<<<B / 4, 256, 0, stream>>>(emb, posOf, pack, B);
    gemm_tail_kernel<<<512, 256, 0, stream>>>(pack, famSorted, famLoHi, pMin, pMax,
                                              counters, partial, (float*)d_out, B);
}